// Round 6
// baseline (763.056 us; speedup 1.0000x reference)
//
#include <hip/hip_runtime.h>
#include <stdint.h>

// TopkActivation: per-row top-k (k=64) over H=32768 fp32, scatter into zeros.
// Speculative-threshold single-pass:
//   - 8 float4 loads + 8 zero-stores issued together (stores independent of
//     loads -> read+write streams overlap like a copy kernel)
//   - elements with key > f2mono(2.25) collected into LDS via wave-aggregated
//     ballot (expected ~400/row for N(0,1); k=64 at 17 sigma, CAP=1024 at 31)
//   - exact rank (value desc, index asc == jax.lax.top_k tie rule) over the
//     candidate set; candidate ranks == global ranks since every
//     non-candidate is strictly below every candidate
//   - __syncthreads (vmcnt drain) orders bulk zero-stores before <=64 winner
//     scatters; 8 co-resident blocks/CU hide the drain
//   - exact histogram fallback (row kept in regs) if speculation ever fails;
//     never taken for Gaussian data, costs nothing on the hot path.

#define H_DIM    32768
#define NTHREADS 256
#define NITER    (H_DIM / (NTHREADS * 4))   // 8 float4 per thread
#define CAP      1024
#define NBINS    2048
#define NWAVES   (NTHREADS / 64)            // 4
#define BPT      (NBINS / NTHREADS)         // 8

typedef float f32x4 __attribute__((ext_vector_type(4)));

__device__ __forceinline__ uint32_t f2mono(float f) {
    uint32_t u = __float_as_uint(f);
    return (u & 0x80000000u) ? ~u : (u | 0x80000000u);
}
__device__ __forceinline__ float mono2f(uint32_t m) {
    uint32_t u = (m & 0x80000000u) ? (m & 0x7fffffffu) : ~m;
    return __uint_as_float(u);
}

// LDS-visibility barrier WITHOUT vmcnt drain.
__device__ __forceinline__ void BARLDS() {
    asm volatile("s_waitcnt lgkmcnt(0)" ::: "memory");
    __builtin_amdgcn_s_barrier();
}

__global__ __launch_bounds__(NTHREADS, 8)   // 8 waves/EU -> 8 blocks/CU
void topk_kernel(const float* __restrict__ in, const int* __restrict__ kp,
                 float* __restrict__ out)
{
    __shared__ uint32_t cand_u[CAP];
    __shared__ uint32_t cand_i[CAP];
    __shared__ uint32_t hist[NBINS];        // fallback only
    __shared__ uint32_t wave_tot[NWAVES];
    __shared__ uint32_t s_b, s_g, s_cnt, s_ncand;

    const uint32_t t    = threadIdx.x;
    const uint32_t row  = blockIdx.x;
    const uint32_t k    = (uint32_t)kp[0];
    const uint32_t lane = t & 63;

    const f32x4* __restrict__ rin  = (const f32x4*)(in  + (size_t)row * H_DIM);
    f32x4*       __restrict__ rout = (f32x4*)(out + (size_t)row * H_DIM);

    if (t == 0) s_ncand = 0;

    // ---- issue all loads and all zero-stores; fully independent streams
    f32x4 v[NITER];
    #pragma unroll
    for (int i = 0; i < NITER; ++i) v[i] = rin[t + i * NTHREADS];
    const f32x4 z = {0.f, 0.f, 0.f, 0.f};
    #pragma unroll
    for (int i = 0; i < NITER; ++i) rout[t + i * NTHREADS] = z;

    BARLDS();   // s_ncand=0 visible; no vmcnt drain

    // ---- wave-aggregated candidate collection: key > TMONO
    const uint32_t TMONO = f2mono(2.25f);
    #pragma unroll
    for (int i = 0; i < NITER; ++i) {
        #pragma unroll
        for (int c = 0; c < 4; ++c) {
            uint32_t u = f2mono(v[i][c]);
            bool cand = u > TMONO;
            unsigned long long m = __ballot(cand);
            if (m) {                              // wave-uniform
                uint32_t base = 0;
                if (lane == 0) base = atomicAdd(&s_ncand, (uint32_t)__popcll(m));
                base = (uint32_t)__shfl((int)base, 0);
                if (cand) {
                    uint32_t pos = base + (uint32_t)__popcll(m & ((1ull << lane) - 1ull));
                    if (pos < CAP) {
                        cand_u[pos] = u;
                        cand_i[pos] = (t + (uint32_t)i * NTHREADS) * 4u + (uint32_t)c;
                    }
                }
            }
        }
    }
    __syncthreads();   // drains zero-stores (vmcnt 0) + publishes candidates

    const uint32_t nc = s_ncand;
    if (nc >= k && nc <= CAP) {
        // ---- fast path: exact rank over candidates, scatter winners
        for (uint32_t i = t; i < nc; i += NTHREADS) {
            uint32_t ui = cand_u[i], ii = cand_i[i];
            uint32_t rank = 0;
            for (uint32_t j = 0; j < nc; ++j) {
                uint32_t uj = cand_u[j];
                rank += (uj > ui || (uj == ui && cand_i[j] < ii)) ? 1u : 0u;
            }
            if (rank < k) out[(size_t)row * H_DIM + ii] = mono2f(ui);
        }
        return;   // block-uniform
    }

    // ================= exact fallback (speculation failed) =================
    // Row is still in v[]; no global re-read needed.
    for (int i = 0; i < NBINS / NTHREADS; ++i) hist[t + i * NTHREADS] = 0;
    if (t == 0) s_ncand = 0;
    __syncthreads();

    #pragma unroll
    for (int i = 0; i < NITER; ++i)
        #pragma unroll
        for (int c = 0; c < 4; ++c)
            atomicAdd(&hist[f2mono(v[i][c]) >> 21], 1u);
    __syncthreads();

    // boundary bin: cumAbove < k <= cumAbove + bin
    {
        uint32_t h[BPT];
        uint32_t s = 0;
        #pragma unroll
        for (int bb = 0; bb < BPT; ++bb) { h[bb] = hist[BPT * t + bb]; s += h[bb]; }
        uint32_t vv = s;
        #pragma unroll
        for (int off = 1; off < 64; off <<= 1) {     // inclusive suffix scan
            uint32_t o = __shfl_down(vv, off);
            if (lane + off < 64) vv += o;
        }
        if (lane == 0) wave_tot[t >> 6] = vv;
        __syncthreads();
        uint32_t acc = 0;
        for (int w = 0; w < NWAVES; ++w) if ((uint32_t)w > (t >> 6)) acc += wave_tot[w];
        const uint32_t Ech = vv + acc - s;
        if (Ech < k && k <= Ech + s) {
            uint32_t gl = Ech;
            #pragma unroll
            for (int bb = BPT - 1; bb >= 0; --bb) {
                if (gl + h[bb] >= k) { s_b = BPT * t + (uint32_t)bb; s_g = gl; s_cnt = h[bb]; break; }
                gl += h[bb];
            }
        }
    }
    __syncthreads();

    uint32_t prefix = s_b, g = s_g, cnt = s_cnt, shift = 21;

    while (cnt > CAP && shift > 0) {
        uint32_t nshift = (shift >= 11) ? (shift - 11) : 0;
        uint32_t nbits  = shift - nshift;
        uint32_t nbins  = 1u << nbits;
        __syncthreads();
        for (uint32_t i2 = t; i2 < nbins; i2 += NTHREADS) hist[i2] = 0;
        __syncthreads();
        #pragma unroll
        for (int i = 0; i < NITER; ++i)
            #pragma unroll
            for (int c = 0; c < 4; ++c) {
                uint32_t u = f2mono(v[i][c]);
                if ((u >> shift) == prefix)
                    atomicAdd(&hist[(u >> nshift) & (nbins - 1)], 1u);
            }
        __syncthreads();
        if (t == 0) {
            uint32_t gl = g;
            for (int bb = (int)nbins - 1; bb >= 0; --bb) {
                uint32_t hh = hist[bb];
                if (gl + hh >= k) { s_b = (uint32_t)bb; s_g = gl; s_cnt = hh; break; }
                gl += hh;
            }
        }
        __syncthreads();
        prefix = (prefix << nbits) | s_b;
        g = s_g; cnt = s_cnt; shift = nshift;
    }

    if (shift == 0 && cnt > CAP) {
        // tie-flood: boundary elements all share one key; lowest indices win.
        const uint32_t need2 = k - g;
        uint32_t base = 0;
        for (int i = 0; i < NITER; ++i) {
            uint32_t my = 0, mc[4];
            #pragma unroll
            for (int c = 0; c < 4; ++c) {
                bool b = ((f2mono(v[i][c]) >> shift) > prefix);
                if ((f2mono(v[i][c])) > prefix && shift == 0) {}  // (unused)
                mc[c] = my;
                my += (f2mono(v[i][c]) == prefix) ? 1u : 0u;
            }
            // also write strictly-above values in this same sweep
            #pragma unroll
            for (int c = 0; c < 4; ++c)
                if (f2mono(v[i][c]) > prefix)
                    out[(size_t)row * H_DIM + (t + (uint32_t)i * NTHREADS) * 4u + (uint32_t)c] = v[i][c];
            uint32_t pre = my;
            for (int off = 1; off < 64; off <<= 1) {
                uint32_t o = __shfl_up(pre, off);
                if (lane >= (uint32_t)off) pre += o;
            }
            if (lane == 63) wave_tot[t >> 6] = pre;
            __syncthreads();
            uint32_t wbase = 0, tot = 0;
            for (int w = 0; w < NWAVES; ++w) {
                if ((uint32_t)w < (t >> 6)) wbase += wave_tot[w];
                tot += wave_tot[w];
            }
            uint32_t excl = base + wbase + pre - my;
            #pragma unroll
            for (int c = 0; c < 4; ++c)
                if (f2mono(v[i][c]) == prefix && excl + mc[c] < need2)
                    out[(size_t)row * H_DIM + (t + (uint32_t)i * NTHREADS) * 4u + (uint32_t)c] = mono2f(prefix);
            base += tot;
            __syncthreads();
        }
        return;
    }

    // general fallback: scatter strictly-above values, collect boundary cands
    #pragma unroll
    for (int i = 0; i < NITER; ++i)
        #pragma unroll
        for (int c = 0; c < 4; ++c) {
            uint32_t u  = f2mono(v[i][c]);
            uint32_t hi = u >> shift;
            uint32_t ii = (t + (uint32_t)i * NTHREADS) * 4u + (uint32_t)c;
            if (hi > prefix) {
                out[(size_t)row * H_DIM + ii] = v[i][c];
            } else if (hi == prefix) {
                uint32_t p = atomicAdd(&s_ncand, 1u);
                if (p < CAP) { cand_u[p] = u; cand_i[p] = ii; }
            }
        }
    __syncthreads();

    {
        const uint32_t need = k - g;
        uint32_t n2 = s_ncand; if (n2 > CAP) n2 = CAP;
        for (uint32_t i = t; i < n2; i += NTHREADS) {
            uint32_t ui = cand_u[i], ii = cand_i[i];
            uint32_t rank = 0;
            for (uint32_t j = 0; j < n2; ++j) {
                uint32_t uj = cand_u[j];
                rank += (uj > ui || (uj == ui && cand_i[j] < ii)) ? 1u : 0u;
            }
            if (rank < need) out[(size_t)row * H_DIM + ii] = mono2f(ui);
        }
    }
}

extern "C" void kernel_launch(void* const* d_in, const int* in_sizes, int n_in,
                              void* d_out, int out_size, void* d_ws, size_t ws_size,
                              hipStream_t stream)
{
    const float* x  = (const float*)d_in[0];
    const int*   kp = (const int*)d_in[1];
    float* out = (float*)d_out;
    const int B = in_sizes[0] / H_DIM;
    hipLaunchKernelGGL(topk_kernel, dim3(B), dim3(NTHREADS), 0, stream, x, kp, out);
}

// Round 7
// 297.245 us; speedup vs baseline: 2.5671x; 2.5671x over previous
//
#include <hip/hip_runtime.h>
#include <stdint.h>

// TopkActivation: per-row top-k (k=64) over H=32768 fp32, scatter into zeros.
//
// Design (constraint-driven, rounds 1-6):
//  * A row of keys (128 KB) cannot live in registers together with >1
//    resident block (512 KB RF/CU) -> every bounded-occupancy attempt spilled.
//  * So: row lives in LDS (128 KB of the 160 KB/CU); registers only ever hold
//    the NEXT row's 8 float4 loads (32 VGPR) -> no spill, compiler free.
//  * Persistent blocks (grid=256, 16 rows each) software-pipeline rows:
//    while row r is histogrammed/scanned/ranked/written FROM LDS, row r+1's
//    global loads are in flight into buf[]. All barriers are raw
//    s_waitcnt lgkmcnt(0) + s_barrier (cross-thread state is LDS-only), so
//    loads AND output stores are never drained by a barrier -> HBM keeps two
//    continuous streams (copy-kernel style).
//  * Winner-marking LDS bitmap -> exactly ONE global store per element,
//    issued in the final pass and never awaited in-kernel.
//  * Selection: 4096-bin histogram of top-12 bits of an order-preserving
//    monotonic key; exact rank of the ~30 boundary-bin candidates with
//    jax.lax.top_k tie semantics (equal values -> lower index wins).
//    Cold exact fallbacks (refine / tie-flood) read keys back from LDS.

#define H_DIM    32768
#define NTHREADS 1024
#define NITER    (H_DIM / (NTHREADS * 4))   // 8 float4 per thread
#define CAP      512
#define NBINS    4096
#define NWAVES   (NTHREADS / 64)            // 16
#define BPT      (NBINS / NTHREADS)         // 4 bins/thread in scan
#define NWORDS   (H_DIM / 32)               // 1024 bitmap words

typedef float f32x4 __attribute__((ext_vector_type(4)));

__device__ __forceinline__ uint32_t f2mono(float f) {
    uint32_t u = __float_as_uint(f);
    return (u & 0x80000000u) ? ~u : (u | 0x80000000u);
}
__device__ __forceinline__ float mono2f(uint32_t m) {
    uint32_t u = (m & 0x80000000u) ? (m & 0x7fffffffu) : ~m;
    return __uint_as_float(u);
}

// LDS-visibility barrier WITHOUT vmcnt drain: keeps global loads/stores in
// flight. Every piece of cross-thread state in this kernel lives in LDS.
__device__ __forceinline__ void BARLDS() {
    asm volatile("s_waitcnt lgkmcnt(0)" ::: "memory");
    __builtin_amdgcn_s_barrier();
}

__global__ __launch_bounds__(NTHREADS)      // no min-wave bound: never force spill
void topk_kernel(const float* __restrict__ in, const int* __restrict__ kp,
                 float* __restrict__ out, int B)
{
    __shared__ uint32_t rowk[H_DIM];        // 128 KB: monotonic keys of row
    __shared__ uint32_t hist[NBINS];        // 16 KB
    __shared__ uint32_t bitmap[NWORDS];     // 4 KB winner bits
    __shared__ uint32_t cand_u[CAP];        // 2 KB
    __shared__ uint32_t cand_i[CAP];        // 2 KB
    __shared__ uint32_t wave_tot[NWAVES];
    __shared__ uint32_t s_b, s_g, s_cnt, s_ncand;

    uint4* rowk4 = (uint4*)rowk;

    const uint32_t t    = threadIdx.x;
    const uint32_t k    = (uint32_t)kp[0];
    const uint32_t lane = t & 63;
    const uint32_t wid  = t >> 6;

    int r = (int)blockIdx.x;
    const int rstep = (int)gridDim.x;

    // ---- prologue: prefetch first row into registers
    f32x4 buf[NITER];
    if (r < B) {
        const f32x4* __restrict__ rin = (const f32x4*)(in + (size_t)r * H_DIM);
        #pragma unroll
        for (int i = 0; i < NITER; ++i)
            buf[i] = __builtin_nontemporal_load(&rin[t + i * NTHREADS]);
    }

    for (; r < B; r += rstep) {
        BARLDS();  // close previous row's LDS reads before overwriting

        // ---- A: zero LDS state; spill buf -> LDS keys + histogram;
        //         issue next-row prefetch into the freed buf regs
        #pragma unroll
        for (int i = 0; i < NBINS / NTHREADS; ++i) hist[t + i * NTHREADS] = 0;
        bitmap[t] = 0;
        if (t == 0) s_ncand = 0;
        BARLDS();

        {
            const int nr = r + rstep;
            const f32x4* __restrict__ rnext =
                (const f32x4*)(in + (size_t)nr * H_DIM);
            #pragma unroll
            for (int i = 0; i < NITER; ++i) {
                uint32_t u0 = f2mono(buf[i].x);
                uint32_t u1 = f2mono(buf[i].y);
                uint32_t u2 = f2mono(buf[i].z);
                uint32_t u3 = f2mono(buf[i].w);
                rowk4[t + i * NTHREADS] = make_uint4(u0, u1, u2, u3);
                atomicAdd(&hist[u0 >> 20], 1u);
                atomicAdd(&hist[u1 >> 20], 1u);
                atomicAdd(&hist[u2 >> 20], 1u);
                atomicAdd(&hist[u3 >> 20], 1u);
                if (nr < B)   // overlaps all phases below
                    buf[i] = __builtin_nontemporal_load(&rnext[t + i * NTHREADS]);
            }
        }
        BARLDS();

        // ---- B: boundary bin b: cumAbove(b) < k <= cumAbove(b) + hist[b]
        {
            uint32_t h[BPT];
            uint32_t s = 0;
            #pragma unroll
            for (int bb = 0; bb < BPT; ++bb) { h[bb] = hist[BPT * t + bb]; s += h[bb]; }
            uint32_t v = s;
            #pragma unroll
            for (int off = 1; off < 64; off <<= 1) {   // inclusive suffix scan
                uint32_t o = __shfl_down(v, off);
                if (lane + off < 64) v += o;
            }
            if (lane == 0) wave_tot[wid] = v;
            BARLDS();
            uint32_t acc = 0;
            #pragma unroll
            for (int w = 0; w < NWAVES; ++w) if ((uint32_t)w > wid) acc += wave_tot[w];
            const uint32_t Ech = v + acc - s;           // strictly-above count
            if (Ech < k && k <= Ech + s) {              // exactly one thread
                uint32_t gl = Ech;
                #pragma unroll
                for (int bb = BPT - 1; bb >= 0; --bb) {
                    if (gl + h[bb] >= k) { s_b = BPT * t + (uint32_t)bb; s_g = gl; s_cnt = h[bb]; break; }
                    gl += h[bb];
                }
            }
        }
        BARLDS();

        uint32_t prefix = s_b;
        uint32_t g      = s_g;
        uint32_t cnt    = s_cnt;
        uint32_t shift  = 20;

        // ---- cold fallback: refine until boundary population fits CAP
        while (cnt > CAP && shift > 0) {
            uint32_t nshift = (shift >= 12) ? (shift - 12) : 0;
            uint32_t nbits  = shift - nshift;
            uint32_t nbins  = 1u << nbits;
            BARLDS();
            for (uint32_t i2 = t; i2 < nbins; i2 += NTHREADS) hist[i2] = 0;
            BARLDS();
            for (int i = 0; i < NITER; ++i) {
                uint4 q = rowk4[t + i * NTHREADS];
                #pragma unroll
                for (int c = 0; c < 4; ++c) {
                    uint32_t u = (&q.x)[c];
                    if ((u >> shift) == prefix)
                        atomicAdd(&hist[(u >> nshift) & (nbins - 1)], 1u);
                }
            }
            BARLDS();
            if (t == 0) {
                uint32_t gl = g;
                for (int bb = (int)nbins - 1; bb >= 0; --bb) {
                    uint32_t hh = hist[bb];
                    if (gl + hh >= k) { s_b = (uint32_t)bb; s_g = gl; s_cnt = hh; break; }
                    gl += hh;
                }
            }
            BARLDS();
            prefix = (prefix << nbits) | s_b;
            g = s_g; cnt = s_cnt; shift = nshift;
        }

        const uint32_t need = k - g;

        if (cnt > CAP) {
            // ---- ultra-cold tie-flood: shift==0, >CAP identical keys at the
            //      boundary; lowest indices win. Serial but obviously correct.
            if (t == 0) {
                uint32_t rem = need;
                for (uint32_t idx = 0; idx < H_DIM && rem; ++idx) {
                    if (rowk[idx] == prefix) {
                        bitmap[idx >> 5] |= 1u << (idx & 31);
                        --rem;
                    }
                }
            }
            BARLDS();
        } else {
            // ---- C: collect boundary-bin candidates from LDS keys
            for (int i = 0; i < NITER; ++i) {
                uint4 q = rowk4[t + i * NTHREADS];
                #pragma unroll
                for (int c = 0; c < 4; ++c) {
                    uint32_t u = (&q.x)[c];
                    if ((u >> shift) == prefix) {
                        uint32_t p = atomicAdd(&s_ncand, 1u);
                        if (p < CAP) {
                            cand_u[p] = u;
                            cand_i[p] = (t + (uint32_t)i * NTHREADS) * 4u + (uint32_t)c;
                        }
                    }
                }
            }
            BARLDS();

            // ---- R: rank (value desc, index asc); winners -> bitmap
            uint32_t nc = s_ncand;
            for (uint32_t i = t; i < nc; i += NTHREADS) {
                uint32_t ui = cand_u[i], ii = cand_i[i];
                uint32_t rank = 0;
                for (uint32_t j = 0; j < nc; ++j) {
                    uint32_t uj = cand_u[j];
                    rank += (uj > ui || (uj == ui && cand_i[j] < ii)) ? 1u : 0u;
                }
                if (rank < need) atomicOr(&bitmap[ii >> 5], 1u << (ii & 31));
            }
            BARLDS();
        }

        // ---- D: single write pass from LDS; stores never awaited in-kernel
        {
            f32x4* __restrict__ rout = (f32x4*)(out + (size_t)r * H_DIM);
            for (int i = 0; i < NITER; ++i) {
                uint4 q = rowk4[t + i * NTHREADS];
                f32x4 o;
                #pragma unroll
                for (int c = 0; c < 4; ++c) {
                    uint32_t u  = (&q.x)[c];
                    uint32_t hi = u >> shift;
                    float val = 0.0f;
                    if (hi > prefix) {
                        val = mono2f(u);
                    } else if (hi == prefix) {
                        uint32_t ii = (t + (uint32_t)i * NTHREADS) * 4u + (uint32_t)c;
                        if ((bitmap[ii >> 5] >> (ii & 31)) & 1u) val = mono2f(u);
                    }
                    o[c] = val;
                }
                __builtin_nontemporal_store(o, &rout[t + i * NTHREADS]);
            }
        }
    }
}

extern "C" void kernel_launch(void* const* d_in, const int* in_sizes, int n_in,
                              void* d_out, int out_size, void* d_ws, size_t ws_size,
                              hipStream_t stream)
{
    const float* x  = (const float*)d_in[0];
    const int*   kp = (const int*)d_in[1];
    float* out = (float*)d_out;
    const int B = in_sizes[0] / H_DIM;
    const int grid = B < 256 ? B : 256;
    hipLaunchKernelGGL(topk_kernel, dim3(grid), dim3(NTHREADS), 0, stream,
                       x, kp, out, B);
}

// Round 8
// 270.360 us; speedup vs baseline: 2.8224x; 1.0994x over previous
//
#include <hip/hip_runtime.h>
#include <stdint.h>

// TopkActivation: per-row top-k (k=64) over H=32768 fp32, scatter into zeros.
//
// Geometry (the only corner of the constraint space rounds 1-7 left open):
//   512 threads/block, one row per block, 64 monotonic keys per thread in
//   REGISTERS (~110 VGPR total) -> two 512-thread blocks co-resident per CU
//   (4 waves/SIMD x ~110 <= 512 VGPR-slot budget), no spill. The two blocks
//   mutually hide each other's LDS phases (hist/scan/rank) and store drains.
//   All barriers are raw lgkmcnt(0)+s_barrier (cross-thread state is LDS-
//   only) so global loads/stores are never drained mid-kernel; winners are
//   marked in an LDS bitmap -> exactly ONE global store per element, issued
//   in the final pass with nothing after it.
// Selection: 4096-bin histogram of the top-12 key bits + exact rank of the
// ~55 boundary-bin candidates; jax.lax.top_k tie semantics (equal values ->
// lower index wins). Exact cold fallbacks (refine / tie-flood) keep keys in
// registers; never taken for Gaussian data.

#define H_DIM    32768
#define NTHREADS 512
#define NITER    (H_DIM / (NTHREADS * 4))   // 16 float4 per thread
#define CAP      1024
#define NBINS    4096
#define NWAVES   (NTHREADS / 64)            // 8
#define BPT      (NBINS / NTHREADS)         // 8 bins/thread in scan
#define NWORDS   (H_DIM / 32)               // 1024 bitmap words

typedef float f32x4 __attribute__((ext_vector_type(4)));

__device__ __forceinline__ uint32_t f2mono(float f) {
    uint32_t u = __float_as_uint(f);
    return (u & 0x80000000u) ? ~u : (u | 0x80000000u);
}
__device__ __forceinline__ float mono2f(uint32_t m) {
    uint32_t u = (m & 0x80000000u) ? (m & 0x7fffffffu) : ~m;
    return __uint_as_float(u);
}

// LDS-visibility barrier WITHOUT vmcnt drain: keeps global streams in flight.
__device__ __forceinline__ void BARLDS() {
    asm volatile("s_waitcnt lgkmcnt(0)" ::: "memory");
    __builtin_amdgcn_s_barrier();
}

__global__ __launch_bounds__(NTHREADS, 2)   // empirical VGPR cap 256/2 = 128
void topk_kernel(const float* __restrict__ in, const int* __restrict__ kp,
                 float* __restrict__ out)
{
    __shared__ uint32_t hist[NBINS];        // 16 KB
    __shared__ uint32_t bitmap[NWORDS];     // 4 KB
    __shared__ uint32_t cand_u[CAP];        // 4 KB
    __shared__ uint32_t cand_i[CAP];        // 4 KB
    __shared__ uint32_t wave_tot[NWAVES];
    __shared__ uint32_t s_b, s_g, s_cnt, s_ncand;

    const uint32_t t    = threadIdx.x;
    const uint32_t row  = blockIdx.x;
    const uint32_t k    = (uint32_t)kp[0];
    const uint32_t lane = t & 63;
    const uint32_t wid  = t >> 6;

    const f32x4* __restrict__ rin = (const f32x4*)(in + (size_t)row * H_DIM);

    // ---- zero LDS state
    #pragma unroll
    for (int i = 0; i < NBINS / NTHREADS; ++i) hist[t + i * NTHREADS] = 0;
    #pragma unroll
    for (int i = 0; i < NWORDS / NTHREADS; ++i) bitmap[t + i * NTHREADS] = 0;
    if (t == 0) s_ncand = 0;
    BARLDS();

    // ---- load row -> register keys (convert immediately) + 12-bit histogram
    uint32_t um[NITER][4];
    #pragma unroll
    for (int i = 0; i < NITER; ++i) {
        f32x4 v = __builtin_nontemporal_load(&rin[t + i * NTHREADS]);
        um[i][0] = f2mono(v.x);
        um[i][1] = f2mono(v.y);
        um[i][2] = f2mono(v.z);
        um[i][3] = f2mono(v.w);
        atomicAdd(&hist[um[i][0] >> 20], 1u);
        atomicAdd(&hist[um[i][1] >> 20], 1u);
        atomicAdd(&hist[um[i][2] >> 20], 1u);
        atomicAdd(&hist[um[i][3] >> 20], 1u);
    }
    BARLDS();

    // ---- boundary bin b: cumAbove(b) < k <= cumAbove(b) + hist[b]
    {
        uint32_t h[BPT];
        uint32_t s = 0;
        #pragma unroll
        for (int bb = 0; bb < BPT; ++bb) { h[bb] = hist[BPT * t + bb]; s += h[bb]; }
        uint32_t v = s;
        #pragma unroll
        for (int off = 1; off < 64; off <<= 1) {       // inclusive suffix scan
            uint32_t o = __shfl_down(v, off);
            if (lane + off < 64) v += o;
        }
        if (lane == 0) wave_tot[wid] = v;
        BARLDS();
        uint32_t acc = 0;                               // suffix over waves > wid
        #pragma unroll
        for (int w = 0; w < NWAVES; ++w) if ((uint32_t)w > wid) acc += wave_tot[w];
        const uint32_t Ech = v + acc - s;               // strictly-above count
        if (Ech < k && k <= Ech + s) {                  // exactly one thread
            uint32_t gl = Ech;
            #pragma unroll
            for (int bb = BPT - 1; bb >= 0; --bb) {
                if (gl + h[bb] >= k) { s_b = BPT * t + (uint32_t)bb; s_g = gl; s_cnt = h[bb]; break; }
                gl += h[bb];
            }
        }
    }
    BARLDS();

    uint32_t prefix = s_b;
    uint32_t g      = s_g;
    uint32_t cnt    = s_cnt;
    uint32_t shift  = 20;

    // ---- cold fallback: refine until boundary population fits CAP
    while (cnt > CAP && shift > 0) {
        uint32_t nshift = (shift >= 12) ? (shift - 12) : 0;
        uint32_t nbits  = shift - nshift;
        uint32_t nbins  = 1u << nbits;
        BARLDS();
        for (uint32_t i2 = t; i2 < nbins; i2 += NTHREADS) hist[i2] = 0;
        BARLDS();
        #pragma unroll
        for (int i = 0; i < NITER; ++i)
            #pragma unroll
            for (int c = 0; c < 4; ++c) {
                uint32_t u = um[i][c];
                if ((u >> shift) == prefix)
                    atomicAdd(&hist[(u >> nshift) & (nbins - 1)], 1u);
            }
        BARLDS();
        if (t == 0) {
            uint32_t gl = g;
            for (int bb = (int)nbins - 1; bb >= 0; --bb) {
                uint32_t hh = hist[bb];
                if (gl + hh >= k) { s_b = (uint32_t)bb; s_g = gl; s_cnt = hh; break; }
                gl += hh;
            }
        }
        BARLDS();
        prefix = (prefix << nbits) | s_b;
        g = s_g; cnt = s_cnt; shift = nshift;
    }

    const uint32_t need = k - g;

    if (cnt > CAP) {
        // ---- ultra-cold tie-flood: shift==0, >CAP identical boundary keys;
        //      first `need` in global index order win. idx = 2048*i + 4*t + c
        //      is lexicographic in (i, t, c) -> chunk-by-chunk block scan.
        uint32_t base = 0;
        for (int i = 0; i < NITER; ++i) {
            uint32_t mc[4];
            uint32_t m = 0;
            #pragma unroll
            for (int c = 0; c < 4; ++c) { mc[c] = m; m += (um[i][c] == prefix) ? 1u : 0u; }
            uint32_t pre = m;                           // inclusive scan over t
            #pragma unroll
            for (int off = 1; off < 64; off <<= 1) {
                uint32_t o = __shfl_up(pre, off);
                if (lane >= (uint32_t)off) pre += o;
            }
            if (lane == 63) wave_tot[wid] = pre;
            BARLDS();
            uint32_t wbase = 0, tot = 0;
            #pragma unroll
            for (int w = 0; w < NWAVES; ++w) {
                if ((uint32_t)w < wid) wbase += wave_tot[w];
                tot += wave_tot[w];
            }
            const uint32_t excl = base + wbase + (pre - m);
            #pragma unroll
            for (int c = 0; c < 4; ++c)
                if (um[i][c] == prefix && excl + mc[c] < need) {
                    uint32_t ii = (t + (uint32_t)i * NTHREADS) * 4u + (uint32_t)c;
                    atomicOr(&bitmap[ii >> 5], 1u << (ii & 31));
                }
            base += tot;
            BARLDS();                                   // protect wave_tot reuse
        }
    } else {
        // ---- collect boundary-bin candidates (cnt <= CAP exact)
        #pragma unroll
        for (int i = 0; i < NITER; ++i)
            #pragma unroll
            for (int c = 0; c < 4; ++c) {
                uint32_t u = um[i][c];
                if ((u >> shift) == prefix) {
                    uint32_t p = atomicAdd(&s_ncand, 1u);
                    if (p < CAP) {
                        cand_u[p] = u;
                        cand_i[p] = (t + (uint32_t)i * NTHREADS) * 4u + (uint32_t)c;
                    }
                }
            }
        BARLDS();

        // ---- rank (value desc, index asc); winners -> bitmap
        const uint32_t nc = s_ncand;
        for (uint32_t i = t; i < nc; i += NTHREADS) {
            uint32_t ui = cand_u[i], ii = cand_i[i];
            uint32_t rank = 0;
            for (uint32_t j = 0; j < nc; ++j) {
                uint32_t uj = cand_u[j];
                rank += (uj > ui || (uj == ui && cand_i[j] < ii)) ? 1u : 0u;
            }
            if (rank < need) atomicOr(&bitmap[ii >> 5], 1u << (ii & 31));
        }
    }
    BARLDS();

    // ---- single write pass, dead-last; stores never awaited in-kernel
    {
        f32x4* __restrict__ rout = (f32x4*)(out + (size_t)row * H_DIM);
        #pragma unroll
        for (int i = 0; i < NITER; ++i) {
            f32x4 o;
            #pragma unroll
            for (int c = 0; c < 4; ++c) {
                uint32_t u  = um[i][c];
                uint32_t hi = u >> shift;
                float val = 0.0f;
                if (hi > prefix) {
                    val = mono2f(u);
                } else if (hi == prefix) {
                    uint32_t ii = (t + (uint32_t)i * NTHREADS) * 4u + (uint32_t)c;
                    if ((bitmap[ii >> 5] >> (ii & 31)) & 1u) val = mono2f(u);
                }
                o[c] = val;
            }
            __builtin_nontemporal_store(o, &rout[t + i * NTHREADS]);
        }
    }
}

extern "C" void kernel_launch(void* const* d_in, const int* in_sizes, int n_in,
                              void* d_out, int out_size, void* d_ws, size_t ws_size,
                              hipStream_t stream)
{
    const float* x  = (const float*)d_in[0];
    const int*   kp = (const int*)d_in[1];
    float* out = (float*)d_out;
    const int B = in_sizes[0] / H_DIM;
    hipLaunchKernelGGL(topk_kernel, dim3(B), dim3(NTHREADS), 0, stream, x, kp, out);
}